// Round 3
// baseline (1728.876 us; speedup 1.0000x reference)
//
#include <hip/hip_runtime.h>

#define T_STEPS 1024
#define BATCH   256
#define IND     128
#define HID     256
#define OUTD    64

typedef float  f32x4  __attribute__((ext_vector_type(4)));
typedef __bf16 bf16x8 __attribute__((ext_vector_type(8)));

__device__ __forceinline__ bf16x8 cvt8(float4 a, float4 b){
  bf16x8 v;
  v[0]=(__bf16)a.x; v[1]=(__bf16)a.y; v[2]=(__bf16)a.z; v[3]=(__bf16)a.w;
  v[4]=(__bf16)b.x; v[5]=(__bf16)b.y; v[6]=(__bf16)b.z; v[7]=(__bf16)b.w;
  return v;
}

// ---------------------------------------------------------------------------
// Kernel 1: Ux[t,b,h] = sum_k x[t,b,k] * U[h,k]   (bf16 out, M = T*B = 262144)
// ---------------------------------------------------------------------------
__global__ __launch_bounds__(256) void ux_gemm(const float* __restrict__ x,
                                               const float* __restrict__ U,
                                               __bf16* __restrict__ uxz){
  __shared__ bf16x8 Ub[4096];   // 16 nt * 4 c * 64 lanes, 64 KB
  const int tid = threadIdx.x;
  for(int s = tid; s < 4096; s += 256){
    const int l = s & 63, c = (s>>6)&3, nt = s>>8;
    const int n = nt*16 + (l&15), k = c*32 + ((l>>4)<<3);
    const float4* p = (const float4*)(U + n*IND + k);
    Ub[s] = cvt8(p[0], p[1]);
  }
  __syncthreads();
  const int wave = tid>>6, lane = tid&63;
  const int row0 = blockIdx.x*64 + wave*16;
  const int arow = row0 + (lane&15);
  const int kb = (lane>>4)<<3;
  bf16x8 af[4];
  #pragma unroll
  for(int c=0;c<4;c++){
    const float4* p = (const float4*)(x + (size_t)arow*IND + c*32 + kb);
    af[c] = cvt8(p[0], p[1]);
  }
  const int mb = (lane>>4)<<2;
  const int hc = lane&15;
  #pragma unroll
  for(int nt=0;nt<16;nt++){
    f32x4 acc = {0.f,0.f,0.f,0.f};
    #pragma unroll
    for(int c=0;c<4;c++)
      acc = __builtin_amdgcn_mfma_f32_16x16x32_bf16(af[c], Ub[(nt*4+c)*64 + lane], acc, 0,0,0);
    const int h = nt*16 + hc;
    #pragma unroll
    for(int j=0;j<4;j++)
      uxz[(size_t)(row0 + mb + j)*HID + h] = (__bf16)acc[j];
  }
}

// ---------------------------------------------------------------------------
// Kernel 2: persistent scan, operand-swapped MFMA.
// 16 WGs x 256 thr (4 waves, 1/SIMD). Wave w owns outcols [64w, 64w+64).
// MFMA: D[outcol][batch] = A(W rows) x B(state frags):
//   lane&15 = batch col; D rows (4*kg+j) = outcols -> each lane owns
//   4 CONSECUTIVE h per nt for ONE batch row => b64 global/LDS accesses.
// LDS: state frag-major, XOR-swizzled (phys = L ^ bit7<<5 ^ bit8<<6),
// double-buffered; 4 waves read full state (64KB/step vs 128KB before).
// ---------------------------------------------------------------------------
__global__ __launch_bounds__(256,1) void scan_k(
    const float* __restrict__ W_real, const float* __restrict__ b_real,
    const float* __restrict__ W_tau,  const float* __restrict__ b_tau,
    const float* __restrict__ b_U,    __bf16* __restrict__ uxz){
  __shared__ char lds[32768];   // 2 bufs * {Z,T} * 8KB
  const int tid = threadIdx.x, w = tid>>6, lane = tid&63;
  const int ln15 = lane&15, kg = lane>>4;
  const float L2E = 1.44269504088896340736f;

  // Weights as A-fragments: A[m=outcol][k], m = w*64+nt*16+ln15, k = c*32+kg*8
  bf16x8 wr[4][8], wt[4][8];
  #pragma unroll
  for(int nt=0;nt<4;nt++){
    const int n = w*64 + nt*16 + ln15;
    #pragma unroll
    for(int c=0;c<8;c++){
      const int k = c*32 + (kg<<3);
      const float4* pr = (const float4*)(W_real + n*HID + k);
      wr[nt][c] = cvt8(pr[0], pr[1]);
      const float4* pt = (const float4*)(W_tau + n*HID + k);
      wt[nt][c] = cvt8(pt[0], pt[1]);
    }
  }
  // Per-lane biases at owned h = w*64 + nt*16 + 4*kg + j
  float c1[4][4], bru[4][4];
  #pragma unroll
  for(int nt=0;nt<4;nt++)
    #pragma unroll
    for(int j=0;j<4;j++){
      const int h = w*64 + nt*16 + (kg<<2) + j;
      c1[nt][j]  = -L2E*b_tau[h];          // exp2 arg = fma(aT,-L2E,c1)
      bru[nt][j] = b_real[h] + b_U[h];
    }

  for(int s = tid; s < 2048; s += 256)
    ((float4*)lds)[s] = float4{0.f,0.f,0.f,0.f};
  __syncthreads();

  // swizzle: phys = L ^ ((L>>7)&1)<<5 ^ ((L>>8)&1)<<6  (16B blocks intact)
  const int vr = (lane<<4) ^ (((lane>>3)&1)<<5) ^ (((lane>>4)&1)<<6);
  const int wb = w*2048 + (kg>>1)*256 + (ln15<<4) + ((kg&1)<<3);
  const int vw = wb ^ (((ln15>>3)&1)<<5) ^ (((kg>>1)&1)<<6);

  const int row  = blockIdx.x*16 + ln15;        // batch row this lane owns
  const int loff = row*HID + w*64 + (kg<<2);    // element offset, + nt*16

  float zr[4][4];
  #pragma unroll
  for(int nt=0;nt<4;nt++)
    #pragma unroll
    for(int j=0;j<4;j++) zr[nt][j]=0.f;

  uint2 uxr[4];
  #pragma unroll
  for(int nt=0;nt<4;nt++)
    uxr[nt] = *(const uint2*)(uxz + (size_t)loff + nt*16);

  int bo = 0;
  for(int t=0; t<T_STEPS; ++t){
    // prefetch ux[t+1] raw (b64, latency hidden under this step's compute)
    const int tn = (t < T_STEPS-1) ? t+1 : t;
    const __bf16* pn = uxz + (size_t)tn*(BATCH*HID);
    uint2 uxn[4];
    #pragma unroll
    for(int nt=0;nt<4;nt++)
      uxn[nt] = *(const uint2*)(pn + loff + nt*16);

    const char* rp = lds + bo + vr;
    f32x4 aT[4], aR[4];
    #pragma unroll
    for(int nt=0;nt<4;nt++){ aT[nt]=(f32x4){0,0,0,0}; aR[nt]=(f32x4){0,0,0,0}; }
    #pragma unroll
    for(int c=0;c<8;c++){
      const bf16x8 zf = *(const bf16x8*)(rp + c*1024);
      const bf16x8 tf = *(const bf16x8*)(rp + 8192 + c*1024);
      #pragma unroll
      for(int nt=0;nt<4;nt++){
        aT[nt] = __builtin_amdgcn_mfma_f32_16x16x32_bf16(wt[nt][c], zf, aT[nt], 0,0,0);
        aR[nt] = __builtin_amdgcn_mfma_f32_16x16x32_bf16(wr[nt][c], tf, aR[nt], 0,0,0);
      }
    }

    uint2 zpk[4], tpk[4];
    #pragma unroll
    for(int nt=0;nt<4;nt++){
      float uxf[4];
      uxf[0] = __builtin_bit_cast(float, uxr[nt].x << 16);
      uxf[1] = __builtin_bit_cast(float, uxr[nt].x & 0xffff0000u);
      uxf[2] = __builtin_bit_cast(float, uxr[nt].y << 16);
      uxf[3] = __builtin_bit_cast(float, uxr[nt].y & 0xffff0000u);
      unsigned short zh[4], th[4];
      #pragma unroll
      for(int j=0;j<4;j++){
        const float g   = __builtin_amdgcn_exp2f(__builtin_fmaf(aT[nt][j], -L2E, c1[nt][j]));
        const float pre = (aR[nt][j] + bru[nt][j] + uxf[j]) - zr[nt][j];
        const float t0  = 0.1f*pre;
        const float zn  = __builtin_fmaf(t0, g, zr[nt][j] + t0);  // zr+0.1*pre*(1+g)
        zr[nt][j] = zn;
        const float e2  = __builtin_amdgcn_exp2f(zn*(2.f*L2E));
        const float r   = __builtin_amdgcn_rcpf(e2 + 1.f);
        const float tv  = __builtin_fmaf(-2.f, r, 1.f);           // tanh(zn)
        zh[j] = __builtin_bit_cast(unsigned short, (__bf16)zn);
        th[j] = __builtin_bit_cast(unsigned short, (__bf16)tv);
      }
      zpk[nt].x = (unsigned)zh[0] | ((unsigned)zh[1]<<16);
      zpk[nt].y = (unsigned)zh[2] | ((unsigned)zh[3]<<16);
      tpk[nt].x = (unsigned)th[0] | ((unsigned)th[1]<<16);
      tpk[nt].y = (unsigned)th[2] | ((unsigned)th[3]<<16);
      uxr[nt] = uxn[nt];
    }

    char* wp = lds + (bo^16384) + vw;
    #pragma unroll
    for(int nt=0;nt<4;nt++){
      *(uint2*)(wp + nt*512)        = zpk[nt];
      *(uint2*)(wp + 8192 + nt*512) = tpk[nt];
    }
    __syncthreads();

    // zr_t store (slot t) after the barrier: next barrier drains it
    __bf16* ps = uxz + (size_t)t*(BATCH*HID);
    #pragma unroll
    for(int nt=0;nt<4;nt++)
      *(uint2*)(ps + loff + nt*16) = zpk[nt];

    bo ^= 16384;
  }
}

// ---------------------------------------------------------------------------
// Kernel 3: y[m,o] = sum_h zr[m,h] * W_out[o,h] + b_out[o]   (fp32 out)
// ---------------------------------------------------------------------------
__global__ __launch_bounds__(256) void y_gemm(
    const __bf16* __restrict__ zrbuf, const float* __restrict__ W_out,
    const float* __restrict__ b_out, float* __restrict__ y){
  __shared__ bf16x8 Wo[2048];   // 4 nt * 8 c * 64 lanes, 32 KB
  const int tid = threadIdx.x;
  for(int s=tid; s<2048; s+=256){
    const int l = s&63, c = (s>>6)&7, nt = s>>9;
    const int n = nt*16 + (l&15), k = c*32 + ((l>>4)<<3);
    const float4* p = (const float4*)(W_out + n*HID + k);
    Wo[s] = cvt8(p[0], p[1]);
  }
  __syncthreads();
  const int wave = tid>>6, lane = tid&63;
  const int row0 = blockIdx.x*64 + wave*16;
  const int kb = (lane>>4)<<3;
  bf16x8 af[8];
  #pragma unroll
  for(int c=0;c<8;c++)
    af[c] = *(const bf16x8*)(zrbuf + (size_t)(row0 + (lane&15))*HID + c*32 + kb);
  f32x4 acc[4];
  #pragma unroll
  for(int nt=0;nt<4;nt++) acc[nt] = (f32x4){0,0,0,0};
  #pragma unroll
  for(int nt=0;nt<4;nt++)
    #pragma unroll
    for(int c=0;c<8;c++)
      acc[nt] = __builtin_amdgcn_mfma_f32_16x16x32_bf16(af[c], Wo[(nt*8+c)*64 + lane], acc[nt], 0,0,0);
  const int mb = (lane>>4)<<2, oc = lane&15;
  #pragma unroll
  for(int nt=0;nt<4;nt++){
    const float bo = b_out[nt*16 + oc];
    #pragma unroll
    for(int j=0;j<4;j++)
      y[(size_t)(row0 + mb + j)*OUTD + nt*16 + oc] = acc[nt][j] + bo;
  }
}

extern "C" void kernel_launch(void* const* d_in, const int* in_sizes, int n_in,
                              void* d_out, int out_size, void* d_ws, size_t ws_size,
                              hipStream_t stream){
  const float* x      = (const float*)d_in[0];
  const float* W_real = (const float*)d_in[1];
  const float* b_real = (const float*)d_in[2];
  // d_in[3] = W_imag, d_in[4] = b_imag : dead (zi never affects zr or y)
  const float* U      = (const float*)d_in[5];
  const float* b_U    = (const float*)d_in[6];
  const float* W_tau  = (const float*)d_in[7];
  const float* b_tau  = (const float*)d_in[8];
  const float* W_out  = (const float*)d_in[9];
  const float* b_out  = (const float*)d_in[10];
  __bf16* uxz = (__bf16*)d_ws;   // T*B*HID bf16 = 128 MiB: holds Ux, then zr_t

  ux_gemm<<<dim3((T_STEPS*BATCH)/64), dim3(256), 0, stream>>>(x, U, uxz);
  scan_k <<<dim3(BATCH/16),           dim3(256), 0, stream>>>(W_real, b_real, W_tau, b_tau, b_U, uxz);
  y_gemm <<<dim3((T_STEPS*BATCH)/64), dim3(256), 0, stream>>>(uxz, W_out, b_out, (float*)d_out);
}

// Round 4
// 1230.587 us; speedup vs baseline: 1.4049x; 1.4049x over previous
//
#include <hip/hip_runtime.h>

#define T_STEPS 1024
#define BATCH   256
#define IND     128
#define HID     256
#define OUTD    64

typedef float  f32x4  __attribute__((ext_vector_type(4)));
typedef __bf16 bf16x8 __attribute__((ext_vector_type(8)));

__device__ __forceinline__ bf16x8 cvt8(float4 a, float4 b){
  bf16x8 v;
  v[0]=(__bf16)a.x; v[1]=(__bf16)a.y; v[2]=(__bf16)a.z; v[3]=(__bf16)a.w;
  v[4]=(__bf16)b.x; v[5]=(__bf16)b.y; v[6]=(__bf16)b.z; v[7]=(__bf16)b.w;
  return v;
}

// ---------------------------------------------------------------------------
// Kernel 1: Ux[t,b,h] = sum_k x[t,b,k] * U[h,k]   (bf16 out, M = T*B = 262144)
// ---------------------------------------------------------------------------
__global__ __launch_bounds__(256) void ux_gemm(const float* __restrict__ x,
                                               const float* __restrict__ U,
                                               __bf16* __restrict__ uxz){
  __shared__ bf16x8 Ub[4096];   // 16 nt * 4 c * 64 lanes, 64 KB
  const int tid = threadIdx.x;
  for(int s = tid; s < 4096; s += 256){
    const int l = s & 63, c = (s>>6)&3, nt = s>>8;
    const int n = nt*16 + (l&15), k = c*32 + ((l>>4)<<3);
    const float4* p = (const float4*)(U + n*IND + k);
    Ub[s] = cvt8(p[0], p[1]);
  }
  __syncthreads();
  const int wave = tid>>6, lane = tid&63;
  const int row0 = blockIdx.x*64 + wave*16;
  const int arow = row0 + (lane&15);
  const int kb = (lane>>4)<<3;
  bf16x8 af[4];
  #pragma unroll
  for(int c=0;c<4;c++){
    const float4* p = (const float4*)(x + (size_t)arow*IND + c*32 + kb);
    af[c] = cvt8(p[0], p[1]);
  }
  const int mb = (lane>>4)<<2;
  const int hc = lane&15;
  #pragma unroll
  for(int nt=0;nt<16;nt++){
    f32x4 acc = {0.f,0.f,0.f,0.f};
    #pragma unroll
    for(int c=0;c<4;c++)
      acc = __builtin_amdgcn_mfma_f32_16x16x32_bf16(af[c], Ub[(nt*4+c)*64 + lane], acc, 0,0,0);
    const int h = nt*16 + hc;
    #pragma unroll
    for(int j=0;j<4;j++)
      uxz[(size_t)(row0 + mb + j)*HID + h] = (__bf16)acc[j];
  }
}

// ---------------------------------------------------------------------------
// Kernel 2: persistent scan, operand-swapped MFMA, 512 thr / 8 waves (2/SIMD).
// Wave w owns outcols [32w, 32w+32) (nt<2). D[outcol][batch]: lane owns 4
// CONSECUTIVE h per nt for ONE batch row => b64 global/LDS accesses.
// LDS: B-frag-major LINEAR (no swizzle): read = stride-1 b128 sweep
// (conflict-free); write = per-wave 512B-contiguous b64 (bank-optimal).
// For nt<2 the chunk index c == w, so wave w writes its own 1KB block.
// Weights persistent: 128 VGPR -> ~210 total, 2 waves/SIMD.
// ---------------------------------------------------------------------------
__global__ __launch_bounds__(512,2) void scan_k(
    const float* __restrict__ W_real, const float* __restrict__ b_real,
    const float* __restrict__ W_tau,  const float* __restrict__ b_tau,
    const float* __restrict__ b_U,    __bf16* __restrict__ uxz){
  __shared__ char lds[32768];   // 2 bufs * {Z 8KB, T 8KB}
  const int tid = threadIdx.x, w = tid>>6, lane = tid&63;
  const int ln15 = lane&15, kg = lane>>4;
  const float L2E = 1.44269504088896340736f;

  // Weights as A-fragments: m = w*32 + nt*16 + ln15, k = c*32 + kg*8
  bf16x8 wr[2][8], wt[2][8];
  #pragma unroll
  for(int nt=0;nt<2;nt++){
    const int n = w*32 + nt*16 + ln15;
    #pragma unroll
    for(int c=0;c<8;c++){
      const int k = c*32 + (kg<<3);
      const float4* pr = (const float4*)(W_real + n*HID + k);
      wr[nt][c] = cvt8(pr[0], pr[1]);
      const float4* pt = (const float4*)(W_tau + n*HID + k);
      wt[nt][c] = cvt8(pt[0], pt[1]);
    }
  }
  // Per-lane biases at owned h = w*32 + nt*16 + 4*kg + j
  float c1[2][4], bru[2][4];
  #pragma unroll
  for(int nt=0;nt<2;nt++)
    #pragma unroll
    for(int j=0;j<4;j++){
      const int h = w*32 + nt*16 + (kg<<2) + j;
      c1[nt][j]  = -L2E*b_tau[h];          // exp2 arg = fma(aT,-L2E,c1)
      bru[nt][j] = b_real[h] + b_U[h];
    }

  for(int s = tid; s < 2048; s += 512)
    ((float4*)lds)[s] = float4{0.f,0.f,0.f,0.f};
  __syncthreads();

  // linear read base; write base: c==w block, lane's slot
  const int vr = lane<<4;
  const int vw = (w<<10) + ((kg>>1)<<8) + (ln15<<4) + ((kg&1)<<3);

  const int row  = blockIdx.x*16 + ln15;        // batch row this lane owns
  const int loff = row*HID + w*32 + (kg<<2);    // element offset, + nt*16

  float zr[2][4];
  #pragma unroll
  for(int nt=0;nt<2;nt++)
    #pragma unroll
    for(int j=0;j<4;j++) zr[nt][j]=0.f;

  uint2 uxr[2];
  #pragma unroll
  for(int nt=0;nt<2;nt++)
    uxr[nt] = *(const uint2*)(uxz + (size_t)loff + nt*16);

  int bo = 0;
  for(int t=0; t<T_STEPS; ++t){
    // prefetch ux[t+1] raw (b64, latency hidden under this step's compute)
    const int tn = (t < T_STEPS-1) ? t+1 : t;
    const __bf16* pn = uxz + (size_t)tn*(BATCH*HID);
    uint2 uxn[2];
    #pragma unroll
    for(int nt=0;nt<2;nt++)
      uxn[nt] = *(const uint2*)(pn + loff + nt*16);

    const char* rp = lds + bo + vr;
    f32x4 aT[2], aR[2];
    #pragma unroll
    for(int nt=0;nt<2;nt++){ aT[nt]=(f32x4){0,0,0,0}; aR[nt]=(f32x4){0,0,0,0}; }
    #pragma unroll
    for(int c=0;c<8;c++){
      const bf16x8 zf = *(const bf16x8*)(rp + c*1024);
      const bf16x8 tf = *(const bf16x8*)(rp + 8192 + c*1024);
      #pragma unroll
      for(int nt=0;nt<2;nt++){
        aT[nt] = __builtin_amdgcn_mfma_f32_16x16x32_bf16(wt[nt][c], zf, aT[nt], 0,0,0);
        aR[nt] = __builtin_amdgcn_mfma_f32_16x16x32_bf16(wr[nt][c], tf, aR[nt], 0,0,0);
      }
    }

    uint2 zpk[2], tpk[2];
    #pragma unroll
    for(int nt=0;nt<2;nt++){
      float uxf[4];
      uxf[0] = __builtin_bit_cast(float, uxr[nt].x << 16);
      uxf[1] = __builtin_bit_cast(float, uxr[nt].x & 0xffff0000u);
      uxf[2] = __builtin_bit_cast(float, uxr[nt].y << 16);
      uxf[3] = __builtin_bit_cast(float, uxr[nt].y & 0xffff0000u);
      unsigned short zh[4], th[4];
      #pragma unroll
      for(int j=0;j<4;j++){
        const float g   = __builtin_amdgcn_exp2f(__builtin_fmaf(aT[nt][j], -L2E, c1[nt][j]));
        const float pre = (aR[nt][j] + bru[nt][j] + uxf[j]) - zr[nt][j];
        const float t0  = 0.1f*pre;
        const float zn  = __builtin_fmaf(t0, g, zr[nt][j] + t0);  // zr+0.1*pre*(1+g)
        zr[nt][j] = zn;
        const float e2  = __builtin_amdgcn_exp2f(zn*(2.f*L2E));
        const float r   = __builtin_amdgcn_rcpf(e2 + 1.f);
        const float tv  = __builtin_fmaf(-2.f, r, 1.f);           // tanh(zn)
        zh[j] = __builtin_bit_cast(unsigned short, (__bf16)zn);
        th[j] = __builtin_bit_cast(unsigned short, (__bf16)tv);
      }
      zpk[nt].x = (unsigned)zh[0] | ((unsigned)zh[1]<<16);
      zpk[nt].y = (unsigned)zh[2] | ((unsigned)zh[3]<<16);
      tpk[nt].x = (unsigned)th[0] | ((unsigned)th[1]<<16);
      tpk[nt].y = (unsigned)th[2] | ((unsigned)th[3]<<16);
      uxr[nt] = uxn[nt];
    }

    char* wp = lds + (bo^16384) + vw;
    #pragma unroll
    for(int nt=0;nt<2;nt++){
      *(uint2*)(wp + nt*512)        = zpk[nt];
      *(uint2*)(wp + 8192 + nt*512) = tpk[nt];
    }
    __syncthreads();

    // zr_t store (slot t) after the barrier: next barrier drains it
    __bf16* ps = uxz + (size_t)t*(BATCH*HID);
    #pragma unroll
    for(int nt=0;nt<2;nt++)
      *(uint2*)(ps + loff + nt*16) = zpk[nt];

    bo ^= 16384;
  }
}

// ---------------------------------------------------------------------------
// Kernel 3: y[m,o] = sum_h zr[m,h] * W_out[o,h] + b_out[o]   (fp32 out)
// ---------------------------------------------------------------------------
__global__ __launch_bounds__(256) void y_gemm(
    const __bf16* __restrict__ zrbuf, const float* __restrict__ W_out,
    const float* __restrict__ b_out, float* __restrict__ y){
  __shared__ bf16x8 Wo[2048];   // 4 nt * 8 c * 64 lanes, 32 KB
  const int tid = threadIdx.x;
  for(int s=tid; s<2048; s+=256){
    const int l = s&63, c = (s>>6)&7, nt = s>>9;
    const int n = nt*16 + (l&15), k = c*32 + ((l>>4)<<3);
    const float4* p = (const float4*)(W_out + n*HID + k);
    Wo[s] = cvt8(p[0], p[1]);
  }
  __syncthreads();
  const int wave = tid>>6, lane = tid&63;
  const int row0 = blockIdx.x*64 + wave*16;
  const int kb = (lane>>4)<<3;
  bf16x8 af[8];
  #pragma unroll
  for(int c=0;c<8;c++)
    af[c] = *(const bf16x8*)(zrbuf + (size_t)(row0 + (lane&15))*HID + c*32 + kb);
  f32x4 acc[4];
  #pragma unroll
  for(int nt=0;nt<4;nt++) acc[nt] = (f32x4){0,0,0,0};
  #pragma unroll
  for(int nt=0;nt<4;nt++)
    #pragma unroll
    for(int c=0;c<8;c++)
      acc[nt] = __builtin_amdgcn_mfma_f32_16x16x32_bf16(af[c], Wo[(nt*8+c)*64 + lane], acc[nt], 0,0,0);
  const int mb = (lane>>4)<<2, oc = lane&15;
  #pragma unroll
  for(int nt=0;nt<4;nt++){
    const float bo = b_out[nt*16 + oc];
    #pragma unroll
    for(int j=0;j<4;j++)
      y[(size_t)(row0 + mb + j)*OUTD + nt*16 + oc] = acc[nt][j] + bo;
  }
}

extern "C" void kernel_launch(void* const* d_in, const int* in_sizes, int n_in,
                              void* d_out, int out_size, void* d_ws, size_t ws_size,
                              hipStream_t stream){
  const float* x      = (const float*)d_in[0];
  const float* W_real = (const float*)d_in[1];
  const float* b_real = (const float*)d_in[2];
  // d_in[3] = W_imag, d_in[4] = b_imag : dead (zi never affects zr or y)
  const float* U      = (const float*)d_in[5];
  const float* b_U    = (const float*)d_in[6];
  const float* W_tau  = (const float*)d_in[7];
  const float* b_tau  = (const float*)d_in[8];
  const float* W_out  = (const float*)d_in[9];
  const float* b_out  = (const float*)d_in[10];
  __bf16* uxz = (__bf16*)d_ws;   // T*B*HID bf16 = 128 MiB: holds Ux, then zr_t

  ux_gemm<<<dim3((T_STEPS*BATCH)/64), dim3(256), 0, stream>>>(x, U, uxz);
  scan_k <<<dim3(BATCH/16),           dim3(512), 0, stream>>>(W_real, b_real, W_tau, b_tau, b_U, uxz);
  y_gemm <<<dim3((T_STEPS*BATCH)/64), dim3(256), 0, stream>>>(uxz, W_out, b_out, (float*)d_out);
}